// Round 1
// baseline (2250.776 us; speedup 1.0000x reference)
//
#include <hip/hip_runtime.h>
#include <math.h>

#define L_SEQ 2048
#define BS 8
#define EMB 512
#define NHEAD 8
#define DH 64
#define NB (BS*NHEAD)   // 64 batch-heads
#define HALF 256        // EMB/2

// ---------------------------------------------------------------- freq table
__global__ void freq_kernel(float* __restrict__ freq) {
    int j = threadIdx.x;  // 0..255
    double r = pow(10000.0, -1.0 / 256.0);
    float rf = (float)r;                       // match reference's f32 r
    freq[j] = (float)pow((double)rf, (double)j);
}

// ---------------------------------------------------------------- pos-emb table [L, EMB]
__global__ __launch_bounds__(256) void pe_kernel(const float* __restrict__ freq,
                                                 float* __restrict__ pe) {
    int l = blockIdx.x;       // 0..2047
    int j = threadIdx.x;      // 0..255
    float ph = (float)l * freq[j];
    pe[l*EMB + 2*j]     = sinf(ph);
    pe[l*EMB + 2*j + 1] = cosf(ph);
}

// ---------------------------------------------------------------- embedding gather + pos add
// emb layout [L, BS, EMB]
__global__ __launch_bounds__(256) void embed_kernel(const int* __restrict__ inputs,
                                                    const float* __restrict__ table,
                                                    const float* __restrict__ pe,
                                                    float* __restrict__ emb) {
    int idx = blockIdx.x*256 + threadIdx.x;    // over L*BS*(EMB/4) = 2,097,152
    int e4 = idx & 127;                        // EMB/4 = 128
    int rb = idx >> 7;                         // l*BS + b
    int b  = rb & 7;
    int l  = rb >> 3;
    int tok = inputs[b*L_SEQ + l];
    float4 tv = reinterpret_cast<const float4*>(table)[(size_t)tok*128 + e4];
    float4 pv = reinterpret_cast<const float4*>(pe)[(size_t)l*128 + e4];
    float4 o;
    o.x = tv.x + pv.x; o.y = tv.y + pv.y; o.z = tv.z + pv.z; o.w = tv.w + pv.w;
    reinterpret_cast<float4*>(emb)[(size_t)rb*128 + e4] = o;
}

// ---------------------------------------------------------------- emb.sum over L -> [BS, EMB]
__global__ __launch_bounds__(256) void embsum_kernel(const float* __restrict__ emb,
                                                     float* __restrict__ embsum) {
    int b  = blockIdx.x;          // 8
    int ec = blockIdx.y;          // 2
    int lc = blockIdx.z;          // 16
    int e  = ec*256 + threadIdx.x;
    float s = 0.f;
    int l0 = lc*128;
    for (int l = l0; l < l0+128; l++)
        s += emb[((size_t)l*BS + b)*EMB + e];
    atomicAdd(&embsum[b*EMB + e], s);
}

// ---------------------------------------------------------------- QKV GEMM (f32) + scatter
// C[M=16384, N=1536] = emb @ qkv_w^T + qkv_b, scattered to q/k/v [NB, L, DH]
__global__ __launch_bounds__(256) void qkv_gemm_kernel(const float* __restrict__ A,
                                                       const float* __restrict__ W,
                                                       const float* __restrict__ bias,
                                                       float* __restrict__ qg,
                                                       float* __restrict__ kg,
                                                       float* __restrict__ vg) {
    __shared__ float sa[32][68];   // [k][m], padded, 16B-aligned rows
    __shared__ float sb[32][68];   // [k][n]
    int nb = blockIdx.x;           // 0..23
    int mb = blockIdx.y;           // 0..255
    int t  = threadIdx.x;
    int tx = t & 15, ty = t >> 4;
    int m0 = mb*64, n0 = nb*64;
    float acc[4][4] = {};
    for (int k0 = 0; k0 < 512; k0 += 32) {
        __syncthreads();
        #pragma unroll
        for (int r = 0; r < 2; r++) {
            int idx = t + 256*r;        // 0..511
            int row = idx >> 3;         // 0..63
            int c4  = idx & 7;          // float4 within 32-col strip
            float4 av = reinterpret_cast<const float4*>(A + (size_t)(m0+row)*512 + k0)[c4];
            sa[c4*4+0][row] = av.x; sa[c4*4+1][row] = av.y;
            sa[c4*4+2][row] = av.z; sa[c4*4+3][row] = av.w;
            float4 bv = reinterpret_cast<const float4*>(W + (size_t)(n0+row)*512 + k0)[c4];
            sb[c4*4+0][row] = bv.x; sb[c4*4+1][row] = bv.y;
            sb[c4*4+2][row] = bv.z; sb[c4*4+3][row] = bv.w;
        }
        __syncthreads();
        #pragma unroll
        for (int kk = 0; kk < 32; kk++) {
            float4 a4 = *reinterpret_cast<const float4*>(&sa[kk][ty<<2]);
            float4 b4 = *reinterpret_cast<const float4*>(&sb[kk][tx<<2]);
            float av[4] = {a4.x, a4.y, a4.z, a4.w};
            float bv[4] = {b4.x, b4.y, b4.z, b4.w};
            #pragma unroll
            for (int i = 0; i < 4; i++)
                #pragma unroll
                for (int j = 0; j < 4; j++)
                    acc[i][j] += av[i]*bv[j];
        }
    }
    // scatter: whole 64-wide n-tile maps to one of q/k/v of one head
    int h   = n0 / 192;
    int sel = (n0 % 192) / 64;
    float* dst = (sel == 0) ? qg : (sel == 1) ? kg : vg;
    #pragma unroll
    for (int i = 0; i < 4; i++) {
        int m = m0 + ty*4 + i;
        int l = m >> 3, b = m & 7;
        size_t base = ((size_t)(b*NHEAD + h) * L_SEQ + l) * DH;
        #pragma unroll
        for (int j = 0; j < 4; j++) {
            int n = n0 + tx*4 + j;
            dst[base + (n & 63)] = acc[i][j] + bias[n];
        }
    }
}

// ---------------------------------------------------------------- attention-sum
// per (batch-head, q-chunk of 256): thread = one query; online softmax; O += o_q/l_q
__global__ __launch_bounds__(256) void attn_kernel(const float* __restrict__ qg,
                                                   const float* __restrict__ kg,
                                                   const float* __restrict__ vg,
                                                   float* __restrict__ O) {
    __shared__ float sk[64][64];
    __shared__ float sv[64][64];
    int bidx = blockIdx.x;                       // 0..63
    int t    = threadIdx.x;
    int qi   = blockIdx.y*256 + t;

    float qreg[64];
    {
        const float4* src = reinterpret_cast<const float4*>(qg + ((size_t)bidx*L_SEQ + qi)*DH);
        #pragma unroll
        for (int i = 0; i < 16; i++) {
            float4 tv = src[i];
            qreg[4*i]=tv.x; qreg[4*i+1]=tv.y; qreg[4*i+2]=tv.z; qreg[4*i+3]=tv.w;
        }
    }
    float o[64];
    #pragma unroll
    for (int d = 0; d < 64; d++) o[d] = 0.f;
    float m = -INFINITY, lsum = 0.f;

    const float4* ksrc = reinterpret_cast<const float4*>(kg + (size_t)bidx*L_SEQ*DH);
    const float4* vsrc = reinterpret_cast<const float4*>(vg + (size_t)bidx*L_SEQ*DH);
    float4* kdst = reinterpret_cast<float4*>(&sk[0][0]);
    float4* vdst = reinterpret_cast<float4*>(&sv[0][0]);

    for (int k0 = 0; k0 < L_SEQ; k0 += 64) {
        __syncthreads();
        int base = k0*16;
        #pragma unroll
        for (int i = 0; i < 4; i++) {
            kdst[t + 256*i] = ksrc[base + t + 256*i];
            vdst[t + 256*i] = vsrc[base + t + 256*i];
        }
        __syncthreads();
        #pragma unroll 1
        for (int kk = 0; kk < 64; kk++) {
            const float4* krow = reinterpret_cast<const float4*>(&sk[kk][0]);
            float s0=0.f, s1=0.f, s2=0.f, s3=0.f;
            #pragma unroll
            for (int i = 0; i < 16; i += 4) {
                float4 ka = krow[i], kb = krow[i+1], kc = krow[i+2], kd = krow[i+3];
                s0 += qreg[4*i+0]*ka.x + qreg[4*i+1]*ka.y + qreg[4*i+2]*ka.z + qreg[4*i+3]*ka.w;
                s1 += qreg[4*i+4]*kb.x + qreg[4*i+5]*kb.y + qreg[4*i+6]*kb.z + qreg[4*i+7]*kb.w;
                s2 += qreg[4*i+8]*kc.x + qreg[4*i+9]*kc.y + qreg[4*i+10]*kc.z + qreg[4*i+11]*kc.w;
                s3 += qreg[4*i+12]*kd.x + qreg[4*i+13]*kd.y + qreg[4*i+14]*kd.z + qreg[4*i+15]*kd.w;
            }
            float s = ((s0+s1)+(s2+s3)) * 0.125f;
            if (s != 0.0f) {                        // reference: mask = (scores == 0)
                if (s > m) {
                    float alpha = __expf(m - s);    // exp(-inf)=0 on first hit
                    m = s;
                    lsum *= alpha;
                    #pragma unroll
                    for (int d = 0; d < 64; d++) o[d] *= alpha;
                }
                float p = __expf(s - m);
                lsum += p;
                const float4* vrow = reinterpret_cast<const float4*>(&sv[kk][0]);
                #pragma unroll
                for (int i = 0; i < 16; i++) {
                    float4 vv = vrow[i];
                    o[4*i+0] += p*vv.x; o[4*i+1] += p*vv.y;
                    o[4*i+2] += p*vv.z; o[4*i+3] += p*vv.w;
                }
            }
        }
    }
    float inv = (lsum > 0.f) ? 1.0f/lsum : 0.f;
    #pragma unroll
    for (int d = 0; d < 64; d++) o[d] *= inv;
    // wave-64 butterfly reduce each component
    #pragma unroll
    for (int st = 1; st < 64; st <<= 1) {
        #pragma unroll
        for (int d = 0; d < 64; d++) o[d] += __shfl_xor(o[d], st);
    }
    if ((t & 63) == 0) {
        #pragma unroll
        for (int d = 0; d < 64; d++) atomicAdd(&O[bidx*64 + d], o[d]);
    }
}

// ---------------------------------------------------------------- GroupNorm + residual + LN + MLP
__global__ __launch_bounds__(256) void finalize_kernel(const float* __restrict__ O,
                                                       const float* __restrict__ embsum,
                                                       const int* __restrict__ lens,
                                                       const float* __restrict__ gn_w,
                                                       const float* __restrict__ gn_b,
                                                       const float* __restrict__ ln_w,
                                                       const float* __restrict__ ln_b,
                                                       const float* __restrict__ w1,
                                                       const float* __restrict__ b1,
                                                       const float* __restrict__ w2,
                                                       const float* __restrict__ b2,
                                                       float* __restrict__ out) {
    int b = blockIdx.x;
    int t = threadIdx.x;
    __shared__ float x[EMB];
    __shared__ float xn[EMB];
    __shared__ float h1[2*EMB];
    __shared__ float rbuf[16];

    // GroupNorm over dh per head
    {
        int h = t >> 5;            // 0..7
        int i32 = t & 31;
        float v0 = O[b*EMB + h*64 + i32];
        float v1 = O[b*EMB + h*64 + i32 + 32];
        float s = v0+v1, ss = v0*v0 + v1*v1;
        #pragma unroll
        for (int off = 16; off >= 1; off >>= 1) {
            s  += __shfl_xor(s,  off, 32);
            ss += __shfl_xor(ss, off, 32);
        }
        float mu  = s * (1.f/64.f);
        float var = ss * (1.f/64.f) - mu*mu;
        float rstd = rsqrtf(var + 1e-5f);
        float gw = gn_w[h], gb = gn_b[h];
        float len = (float)lens[b];
        x[h*64+i32]    = (v0-mu)*rstd*gw + gb + embsum[b*EMB + h*64+i32] / len;
        x[h*64+i32+32] = (v1-mu)*rstd*gw + gb + embsum[b*EMB + h*64+i32+32] / len;
    }
    __syncthreads();
    // LayerNorm over EMB
    float xv0 = x[t], xv1 = x[t+256];
    {
        float s = xv0+xv1, ss = xv0*xv0 + xv1*xv1;
        #pragma unroll
        for (int off = 32; off >= 1; off >>= 1) {
            s  += __shfl_xor(s,  off);
            ss += __shfl_xor(ss, off);
        }
        int wid = t >> 6;
        if ((t & 63) == 0) { rbuf[wid] = s; rbuf[8+wid] = ss; }
        __syncthreads();
        float S  = rbuf[0]+rbuf[1]+rbuf[2]+rbuf[3];
        float SS = rbuf[8]+rbuf[9]+rbuf[10]+rbuf[11];
        float mu  = S * (1.f/512.f);
        float var = SS * (1.f/512.f) - mu*mu;
        float rstd = rsqrtf(var + 1e-5f);
        xn[t]     = (xv0-mu)*rstd*ln_w[t]     + ln_b[t];
        xn[t+256] = (xv1-mu)*rstd*ln_w[t+256] + ln_b[t+256];
    }
    __syncthreads();
    // h1 = tanh(xn @ w1^T + b1)
    #pragma unroll
    for (int r = 0; r < 4; r++) {
        int j = t + 256*r;
        const float4* wr = reinterpret_cast<const float4*>(w1 + (size_t)j*512);
        float a0=0.f, a1=0.f;
        #pragma unroll 8
        for (int i = 0; i < 128; i += 2) {
            float4 wv = wr[i];
            float4 xv = *reinterpret_cast<const float4*>(&xn[4*i]);
            a0 += wv.x*xv.x + wv.y*xv.y + wv.z*xv.z + wv.w*xv.w;
            float4 wv1 = wr[i+1];
            float4 xv1 = *reinterpret_cast<const float4*>(&xn[4*i+4]);
            a1 += wv1.x*xv1.x + wv1.y*xv1.y + wv1.z*xv1.z + wv1.w*xv1.w;
        }
        h1[j] = tanhf(a0 + a1 + b1[j]);
    }
    __syncthreads();
    // out = x + h1 @ w2^T + b2
    #pragma unroll
    for (int r = 0; r < 2; r++) {
        int e = t + 256*r;
        const float4* wr = reinterpret_cast<const float4*>(w2 + (size_t)e*1024);
        float a0=0.f, a1=0.f;
        #pragma unroll 8
        for (int i = 0; i < 256; i += 2) {
            float4 wv = wr[i];
            float4 hv = *reinterpret_cast<const float4*>(&h1[4*i]);
            a0 += wv.x*hv.x + wv.y*hv.y + wv.z*hv.z + wv.w*hv.w;
            float4 wv1 = wr[i+1];
            float4 hv1 = *reinterpret_cast<const float4*>(&h1[4*i+4]);
            a1 += wv1.x*hv1.x + wv1.y*hv1.y + wv1.z*hv1.z + wv1.w*hv1.w;
        }
        out[b*EMB + e] = x[e] + a0 + a1 + b2[e];
    }
}

// ---------------------------------------------------------------- launch
extern "C" void kernel_launch(void* const* d_in, const int* in_sizes, int n_in,
                              void* d_out, int out_size, void* d_ws, size_t ws_size,
                              hipStream_t stream) {
    const int*   inputs    = (const int*)d_in[0];
    const int*   lens      = (const int*)d_in[1];
    const float* emb_table = (const float*)d_in[2];
    const float* qkv_w     = (const float*)d_in[3];
    const float* qkv_b     = (const float*)d_in[4];
    const float* gn_w      = (const float*)d_in[5];
    const float* gn_b      = (const float*)d_in[6];
    const float* ln_w      = (const float*)d_in[7];
    const float* ln_b      = (const float*)d_in[8];
    const float* w1        = (const float*)d_in[9];
    const float* b1        = (const float*)d_in[10];
    const float* w2        = (const float*)d_in[11];
    const float* b2        = (const float*)d_in[12];
    float* out = (float*)d_out;

    float* ws = (float*)d_ws;
    const size_t NE = (size_t)L_SEQ*BS*EMB;       // 8,388,608
    float* emb    = ws;
    float* qg     = emb + NE;
    float* kg     = qg  + NE;
    float* vg     = kg  + NE;
    float* pe     = vg  + NE;                     // 1,048,576
    float* freq   = pe  + (size_t)L_SEQ*EMB;      // 256
    float* embsum = freq + 256;                   // 4096
    float* Oacc   = embsum + BS*EMB;              // 4096

    hipMemsetAsync(embsum, 0, 2*BS*EMB*sizeof(float), stream);  // embsum + Oacc

    freq_kernel<<<1, 256, 0, stream>>>(freq);
    pe_kernel<<<L_SEQ, 256, 0, stream>>>(freq, pe);
    embed_kernel<<<(L_SEQ*BS*(EMB/4))/256, 256, 0, stream>>>(inputs, emb_table, pe, emb);
    embsum_kernel<<<dim3(BS, 2, 16), 256, 0, stream>>>(emb, embsum);
    qkv_gemm_kernel<<<dim3(24, 256), 256, 0, stream>>>(emb, qkv_w, qkv_b, qg, kg, vg);
    attn_kernel<<<dim3(NB, L_SEQ/256), 256, 0, stream>>>(qg, kg, vg, Oacc);
    finalize_kernel<<<BS, 256, 0, stream>>>(Oacc, embsum, lens, gn_w, gn_b,
                                            ln_w, ln_b, w1, b1, w2, b2, out);
}